// Round 1
// baseline (25.823 us; speedup 1.0000x reference)
//
#include <hip/hip_runtime.h>

// RankingLoss: pairwise hinge over (pos_i, neg_j) pairs per row.
//   row_sum[b]  = sum_{i: lab=1, j: lab=0} max(MARGIN - s_i + s_j, 0)
//   row_loss[b] = row_sum / max(npos*nneg, 1)
//   out         = mean over rows with npos*nneg > 0 (else 0)
//
// Strategy: O(N^2) pairs (134M total) but compute-light (3 VALU/pair).
// Per block: stage neg-masked scores for a j-chunk in LDS, compact the
// row's pos indices (so no lanes idle under exec mask), each thread owns
// one pos element and sweeps the j-chunk with float4 LDS broadcast reads.

#define MARGIN   0.1f
#define BROWS    32
#define NCOLS    2048
#define THREADS  256
#define TILES_I  (NCOLS / THREADS)   // 8 — covers up to 2048 pos elements
#define J_SPLIT  2
#define JCHUNK   (NCOLS / J_SPLIT)   // 1024

// ws layout: float sums[32] | int npos[32] | int nneg[32]

__global__ __launch_bounds__(THREADS) void rank_pair_kernel(
    const float* __restrict__ scores, const int* __restrict__ labels,
    float* __restrict__ ws)
{
    const int tile  = blockIdx.x;   // which chunk of the pos list
    const int jhalf = blockIdx.y;   // which j-chunk
    const int b     = blockIdx.z;   // row

    __shared__ float tneg[JCHUNK];      // neg? score : -1e30
    __shared__ int   poslist[NCOLS];    // compacted pos indices (unordered)
    __shared__ int   cnt_pos, cnt_neg;
    __shared__ float wsum[THREADS / 64];

    const float* srow = scores + (size_t)b * NCOLS;
    const int*   lrow = labels + (size_t)b * NCOLS;
    const int tid = threadIdx.x;

    if (tid == 0) { cnt_pos = 0; cnt_neg = 0; }
    __syncthreads();

    // Stage this block's j-chunk, masking non-neg entries so they add 0:
    // c + (-1e30) -> fmaxf(...,0) == 0.
    for (int j = tid; j < JCHUNK; j += THREADS) {
        const int gj = jhalf * JCHUNK + j;
        const float s = srow[gj];
        tneg[j] = (lrow[gj] == 0) ? s : -1e30f;
    }
    // Compact pos indices over the FULL row (order irrelevant for a sum).
    for (int idx = tid; idx < NCOLS; idx += THREADS) {
        const int l = lrow[idx];
        if (l == 1) {
            const int p = atomicAdd(&cnt_pos, 1);
            poslist[p] = idx;
        } else if (l == 0) {
            atomicAdd(&cnt_neg, 1);
        }
    }
    __syncthreads();

    const int P = cnt_pos;

    float a0 = 0.f, a1 = 0.f, a2 = 0.f, a3 = 0.f;
    const int my = tile * THREADS + tid;
    if (my < P) {
        const int   i = poslist[my];
        const float c = MARGIN - srow[i];   // L1/L2-cached re-read
        const float4* t4 = (const float4*)tneg;
        #pragma unroll 8
        for (int j4 = 0; j4 < JCHUNK / 4; ++j4) {
            const float4 v = t4[j4];        // LDS broadcast (same addr all lanes)
            a0 += fmaxf(c + v.x, 0.f);
            a1 += fmaxf(c + v.y, 0.f);
            a2 += fmaxf(c + v.z, 0.f);
            a3 += fmaxf(c + v.w, 0.f);
        }
    }
    float acc = (a0 + a1) + (a2 + a3);

    // wave (64-lane) reduce, then cross-wave via LDS
    #pragma unroll
    for (int off = 32; off >= 1; off >>= 1)
        acc += __shfl_down(acc, off, 64);
    const int wave = tid >> 6, lane = tid & 63;
    if (lane == 0) wsum[wave] = acc;
    __syncthreads();

    if (tid == 0) {
        float tot = 0.f;
        #pragma unroll
        for (int w = 0; w < THREADS / 64; ++w) tot += wsum[w];
        atomicAdd(&ws[b], tot);
        if (tile == 0 && jhalf == 0) {
            ((int*)ws)[BROWS + b]     = cnt_pos;
            ((int*)ws)[2 * BROWS + b] = cnt_neg;
        }
    }
}

__global__ __launch_bounds__(64) void rank_finalize_kernel(
    const float* __restrict__ ws, float* __restrict__ out)
{
    const int t = threadIdx.x;
    float loss = 0.f, valid = 0.f;
    if (t < BROWS) {
        const float np = (float)((const int*)ws)[BROWS + t];
        const float nn = (float)((const int*)ws)[2 * BROWS + t];
        const float pairs = np * nn;
        if (pairs > 0.f) { valid = 1.f; loss = ws[t] / pairs; }
    }
    #pragma unroll
    for (int off = 32; off >= 1; off >>= 1) {
        loss  += __shfl_down(loss,  off, 64);
        valid += __shfl_down(valid, off, 64);
    }
    if (t == 0) out[0] = (valid > 0.f) ? (loss / valid) : 0.f;
}

extern "C" void kernel_launch(void* const* d_in, const int* in_sizes, int n_in,
                              void* d_out, int out_size, void* d_ws, size_t ws_size,
                              hipStream_t stream)
{
    const float* scores = (const float*)d_in[0];
    const int*   labels = (const int*)d_in[1];
    float* out = (float*)d_out;
    float* ws  = (float*)d_ws;

    // Zero the per-row sum accumulators each call (ws is NOT re-poisoned
    // between replays; counts are overwritten unconditionally).
    hipMemsetAsync(ws, 0, BROWS * sizeof(float), stream);

    dim3 grid(TILES_I, J_SPLIT, BROWS);
    rank_pair_kernel<<<grid, THREADS, 0, stream>>>(scores, labels, ws);
    rank_finalize_kernel<<<1, 64, 0, stream>>>(ws, out);
}

// Round 2
// 19.884 us; speedup vs baseline: 1.2987x; 1.2987x over previous
//
#include <hip/hip_runtime.h>

// RankingLoss: pairwise hinge over (pos_i, neg_j) pairs per row.
//   row_sum[b]  = sum_{i: lab=1, j: lab=0} max(MARGIN - s_i + s_j, 0)
//   row_loss[b] = row_sum / max(npos*nneg, 1)
//   out         = mean over rows with npos*nneg > 0 (else 0)
//
// R1 changes vs R0:
//  - ballot-based pos compaction (1 lane-0 LDS atomic per wave-iter, not
//    2048 same-address atomics/block -> kills LDS-atomic serialization)
//  - no hipMemsetAsync: each block writes a DISTINCT ws partial slot
//    unconditionally; finalize sums them (poison-safe, 2 dispatches total)
//  - nneg = NCOLS - npos (labels are exactly {0,1} per randint(0,2)),
//    so counts come free from compaction

#define MARGIN   0.1f
#define BROWS    32
#define NCOLS    2048
#define THREADS  256
#define TILES_I  (NCOLS / THREADS)     // 8 — covers up to 2048 pos elements
#define J_SPLIT  2
#define JCHUNK   (NCOLS / J_SPLIT)     // 1024
#define NPART    (TILES_I * J_SPLIT)   // 16 partials per row

// ws layout: float partial[BROWS*NPART] | int npos[BROWS]

__global__ __launch_bounds__(THREADS) void rank_pair_kernel(
    const float* __restrict__ scores, const int* __restrict__ labels,
    float* __restrict__ ws)
{
    const int tile  = blockIdx.x;   // chunk of the compacted pos list
    const int jhalf = blockIdx.y;   // which j-chunk
    const int b     = blockIdx.z;   // row

    __shared__ float tneg[JCHUNK];    // neg? score : -1e30
    __shared__ int   poslist[NCOLS];  // compacted pos indices (unordered)
    __shared__ int   cnt_pos;
    __shared__ float wsum[THREADS / 64];

    const float* srow = scores + (size_t)b * NCOLS;
    const int*   lrow = labels + (size_t)b * NCOLS;
    const int tid  = threadIdx.x;
    const int lane = tid & 63;
    const int wave = tid >> 6;

    if (tid == 0) cnt_pos = 0;
    __syncthreads();

    // Stage this block's j-chunk, masking non-neg entries so they add 0:
    // c + (-1e30) -> fmaxf(...,0) == 0.
    for (int j = tid; j < JCHUNK; j += THREADS) {
        const int gj = jhalf * JCHUNK + j;
        const float s = srow[gj];
        tneg[j] = (lrow[gj] == 0) ? s : -1e30f;
    }

    // Ballot-compact pos indices over the FULL row (order irrelevant).
    #pragma unroll
    for (int it = 0; it < NCOLS / THREADS; ++it) {
        const int idx = it * THREADS + tid;
        const bool ispos = (lrow[idx] == 1);
        const unsigned long long mask = __ballot(ispos);
        int base = 0;
        if (lane == 0) base = atomicAdd(&cnt_pos, (int)__popcll(mask));
        base = __shfl(base, 0, 64);
        if (ispos) {
            const int off = (int)__popcll(mask & ((1ull << lane) - 1ull));
            poslist[base + off] = idx;
        }
    }
    __syncthreads();

    const int P = cnt_pos;

    float a0 = 0.f, a1 = 0.f, a2 = 0.f, a3 = 0.f;
    const int my = tile * THREADS + tid;
    if (my < P) {
        const int   i = poslist[my];
        const float c = MARGIN - srow[i];   // L1/L2-cached gather
        const float4* t4 = (const float4*)tneg;
        #pragma unroll 8
        for (int j4 = 0; j4 < JCHUNK / 4; ++j4) {
            const float4 v = t4[j4];        // LDS broadcast (same addr all lanes)
            a0 += fmaxf(c + v.x, 0.f);
            a1 += fmaxf(c + v.y, 0.f);
            a2 += fmaxf(c + v.z, 0.f);
            a3 += fmaxf(c + v.w, 0.f);
        }
    }
    float acc = (a0 + a1) + (a2 + a3);

    // wave (64-lane) reduce, then cross-wave via LDS
    #pragma unroll
    for (int off = 32; off >= 1; off >>= 1)
        acc += __shfl_down(acc, off, 64);
    if (lane == 0) wsum[wave] = acc;
    __syncthreads();

    if (tid == 0) {
        float tot = 0.f;
        #pragma unroll
        for (int w = 0; w < THREADS / 64; ++w) tot += wsum[w];
        // Distinct slot per block — no memset needed, poison-safe.
        ws[(size_t)b * NPART + jhalf * TILES_I + tile] = tot;
        if (tile == 0 && jhalf == 0)
            ((int*)ws)[BROWS * NPART + b] = P;
    }
}

__global__ __launch_bounds__(64) void rank_finalize_kernel(
    const float* __restrict__ ws, float* __restrict__ out)
{
    const int t = threadIdx.x;
    float loss = 0.f, valid = 0.f;
    if (t < BROWS) {
        float s = 0.f;
        #pragma unroll
        for (int p = 0; p < NPART; ++p) s += ws[t * NPART + p];
        const int   np = ((const int*)ws)[BROWS * NPART + t];
        const int   nn = NCOLS - np;   // labels are exactly {0,1}
        const float pairs = (float)np * (float)nn;
        if (pairs > 0.f) { valid = 1.f; loss = s / pairs; }
    }
    #pragma unroll
    for (int off = 32; off >= 1; off >>= 1) {
        loss  += __shfl_down(loss,  off, 64);
        valid += __shfl_down(valid, off, 64);
    }
    if (t == 0) out[0] = (valid > 0.f) ? (loss / valid) : 0.f;
}

extern "C" void kernel_launch(void* const* d_in, const int* in_sizes, int n_in,
                              void* d_out, int out_size, void* d_ws, size_t ws_size,
                              hipStream_t stream)
{
    const float* scores = (const float*)d_in[0];
    const int*   labels = (const int*)d_in[1];
    float* out = (float*)d_out;
    float* ws  = (float*)d_ws;

    dim3 grid(TILES_I, J_SPLIT, BROWS);
    rank_pair_kernel<<<grid, THREADS, 0, stream>>>(scores, labels, ws);
    rank_finalize_kernel<<<1, 64, 0, stream>>>(ws, out);
}

// Round 3
// 15.621 us; speedup vs baseline: 1.6531x; 1.2729x over previous
//
#include <hip/hip_runtime.h>

// RankingLoss: pairwise hinge over (pos_i, neg_j) pairs per row.
//   row_sum[b]  = sum_{i: lab=1, j: lab=0} max(MARGIN - s_i + s_j, 0)
//   row_loss[b] = row_sum / max(npos*nneg, 1)
//   out         = mean over rows with npos*nneg > 0 (else 0)
//
// R2 changes vs R1 (LDS-pipe was the modeled bottleneck: 1 b128 broadcast
// per 4 pairs = ~5.1 us of LDS pipe; VALU floor is ~2.6 us):
//  - register-tile i: each thread keeps up to 8 c_k = margin - s_i in regs
//    (template-dispatched on block-uniform kcap -> compile-time indexing,
//    no scratch, no inner-loop branches). One b128 broadcast now feeds
//    4*kcap pairs -> LDS pipe drops ~4x below VALU.
//  - perfect balance: every block processes the FULL compacted pos list
//    against its own j-chunk (J_SPLIT=16 -> 512 blocks, 2/CU). No dead
//    tiles whatever P is.
//  - compaction stores c-values (margin - s) directly, no later gather.

#define MARGIN   0.1f
#define BROWS    32
#define NCOLS    2048
#define THREADS  256
#define J_SPLIT  16
#define JCHUNK   (NCOLS / J_SPLIT)   // 128
#define NPART    J_SPLIT             // partials per row
#define KMAX     (NCOLS / THREADS)   // 8

// ws layout: float partial[BROWS*NPART] | int npos[BROWS]

template<int KC>
__device__ __forceinline__ void main_loop(const float* __restrict__ tneg,
                                          const float* __restrict__ c,
                                          float* __restrict__ acc)
{
    const float4* t4 = (const float4*)tneg;
    #pragma unroll
    for (int j8 = 0; j8 < JCHUNK / 8; ++j8) {   // 16 iters
        const float4 v0 = t4[2 * j8];           // LDS broadcast reads
        const float4 v1 = t4[2 * j8 + 1];
        #pragma unroll
        for (int k = 0; k < KC; ++k) {
            const float ck = c[k];
            acc[0] += fmaxf(ck + v0.x, 0.f);
            acc[1] += fmaxf(ck + v0.y, 0.f);
            acc[2] += fmaxf(ck + v0.z, 0.f);
            acc[3] += fmaxf(ck + v0.w, 0.f);
            acc[4] += fmaxf(ck + v1.x, 0.f);
            acc[5] += fmaxf(ck + v1.y, 0.f);
            acc[6] += fmaxf(ck + v1.z, 0.f);
            acc[7] += fmaxf(ck + v1.w, 0.f);
        }
    }
}

__global__ __launch_bounds__(THREADS) void rank_pair_kernel(
    const float* __restrict__ scores, const int* __restrict__ labels,
    float* __restrict__ ws)
{
    const int jb = blockIdx.x;   // j-chunk
    const int b  = blockIdx.y;   // row

    __shared__ float tneg[JCHUNK];   // neg? score : -1e30
    __shared__ float clist[NCOLS];   // compacted c = MARGIN - s (pos only)
    __shared__ int   cnt_pos;
    __shared__ float wsum[THREADS / 64];

    const float* srow = scores + (size_t)b * NCOLS;
    const int*   lrow = labels + (size_t)b * NCOLS;
    const int tid  = threadIdx.x;
    const int lane = tid & 63;
    const int wave = tid >> 6;

    if (tid == 0) cnt_pos = 0;
    __syncthreads();

    // Stage this block's j-chunk (mask non-neg so pairs contribute 0).
    if (tid < JCHUNK) {
        const int gj = jb * JCHUNK + tid;
        const float s = srow[gj];
        tneg[tid] = (lrow[gj] == 0) ? s : -1e30f;
    }

    // Ballot-compact pos c-values over the FULL row (order irrelevant).
    #pragma unroll
    for (int it = 0; it < KMAX; ++it) {
        const int idx = it * THREADS + tid;
        const float s = srow[idx];
        const bool ispos = (lrow[idx] == 1);
        const unsigned long long mask = __ballot(ispos);
        int base = 0;
        if (lane == 0) base = atomicAdd(&cnt_pos, (int)__popcll(mask));
        base = __shfl(base, 0, 64);
        if (ispos) {
            const int off = (int)__popcll(mask & ((1ull << lane) - 1ull));
            clist[base + off] = MARGIN - s;
        }
    }
    __syncthreads();

    const int P = cnt_pos;

    // Per-thread c registers; inactive ranks get -1e30 (pairs -> 0).
    float c[KMAX];
    #pragma unroll
    for (int k = 0; k < KMAX; ++k) {
        const int r = k * THREADS + tid;
        c[k] = (r < P) ? clist[r] : -1e30f;
    }
    const int kcap = (P + THREADS - 1) / THREADS;   // block-uniform, 0..8

    float acc[8] = {0.f, 0.f, 0.f, 0.f, 0.f, 0.f, 0.f, 0.f};
    switch (kcap) {
        case 1: main_loop<1>(tneg, c, acc); break;
        case 2: main_loop<2>(tneg, c, acc); break;
        case 3: main_loop<3>(tneg, c, acc); break;
        case 4: main_loop<4>(tneg, c, acc); break;
        case 5: main_loop<5>(tneg, c, acc); break;
        case 6: main_loop<6>(tneg, c, acc); break;
        case 7: main_loop<7>(tneg, c, acc); break;
        case 8: main_loop<8>(tneg, c, acc); break;
        default: break;  // kcap == 0: no pos in row
    }
    float a = ((acc[0] + acc[1]) + (acc[2] + acc[3]))
            + ((acc[4] + acc[5]) + (acc[6] + acc[7]));

    // wave (64-lane) reduce, then cross-wave via LDS
    #pragma unroll
    for (int off = 32; off >= 1; off >>= 1)
        a += __shfl_down(a, off, 64);
    if (lane == 0) wsum[wave] = a;
    __syncthreads();

    if (tid == 0) {
        float tot = 0.f;
        #pragma unroll
        for (int w = 0; w < THREADS / 64; ++w) tot += wsum[w];
        ws[(size_t)b * NPART + jb] = tot;   // distinct slot, poison-safe
        if (jb == 0)
            ((int*)ws)[BROWS * NPART + b] = P;
    }
}

__global__ __launch_bounds__(64) void rank_finalize_kernel(
    const float* __restrict__ ws, float* __restrict__ out)
{
    const int t = threadIdx.x;
    float loss = 0.f, valid = 0.f;
    if (t < BROWS) {
        float s = 0.f;
        #pragma unroll
        for (int p = 0; p < NPART; ++p) s += ws[t * NPART + p];
        const int np = ((const int*)ws)[BROWS * NPART + t];
        const int nn = NCOLS - np;   // labels are exactly {0,1}
        const float pairs = (float)np * (float)nn;
        if (pairs > 0.f) { valid = 1.f; loss = s / pairs; }
    }
    #pragma unroll
    for (int off = 32; off >= 1; off >>= 1) {
        loss  += __shfl_down(loss,  off, 64);
        valid += __shfl_down(valid, off, 64);
    }
    if (t == 0) out[0] = (valid > 0.f) ? (loss / valid) : 0.f;
}

extern "C" void kernel_launch(void* const* d_in, const int* in_sizes, int n_in,
                              void* d_out, int out_size, void* d_ws, size_t ws_size,
                              hipStream_t stream)
{
    const float* scores = (const float*)d_in[0];
    const int*   labels = (const int*)d_in[1];
    float* out = (float*)d_out;
    float* ws  = (float*)d_ws;

    dim3 grid(J_SPLIT, BROWS);
    rank_pair_kernel<<<grid, THREADS, 0, stream>>>(scores, labels, ws);
    rank_finalize_kernel<<<1, 64, 0, stream>>>(ws, out);
}